// Round 4
// baseline (151.761 us; speedup 1.0000x reference)
//
#include <hip/hip_runtime.h>

typedef __bf16 bf16x8 __attribute__((ext_vector_type(8)));
typedef __bf16 bf16x4 __attribute__((ext_vector_type(4)));
typedef float  f32x4  __attribute__((ext_vector_type(4)));

#define NGRAPH 256
#define HDIM   256
#define DDIM   128
#define ODIM   128
#define NTILES 1600          // 102400 / 64 ; enc grid = NTILES (1 tile/block)

// ---------------------------------------------------------------------------
// prep: swizzle W_enc (fp32 [128][256] row-major) into MFMA B-fragment order
// (bf16), AND zero-init seg (replaces the hipMemsetAsync dispatch).
// Bsw[((kk*16+nt)*64+lane)*8 + j] = W_enc[kk*32+quad*8+j][nt*16+m]
// ---------------------------------------------------------------------------
__global__ __launch_bounds__(256) void prep_kernel(const float* __restrict__ W_enc,
                                                   __bf16* __restrict__ Bsw,
                                                   float* __restrict__ seg) {
  int tid  = blockIdx.x * 256 + threadIdx.x;   // [0, 4096)
  float4 z = {0.f, 0.f, 0.f, 0.f};
#pragma unroll
  for (int p = 0; p < 4; ++p) ((float4*)seg)[tid + p * 4096] = z;

  int lane = tid & 63;
  int t2   = tid >> 6;                          // [0, 64)
  int nt   = t2 & 15;
  int kk   = t2 >> 4;                           // [0, 4)
  int quad = lane >> 4, m = lane & 15;
  int col  = nt * 16 + m;
  bf16x8 frag;
#pragma unroll
  for (int j = 0; j < 8; ++j) {
    int k   = kk * 32 + quad * 8 + j;
    frag[j] = (__bf16)W_enc[k * HDIM + col];
  }
  *(bf16x8*)(Bsw + (size_t)tid * 8) = frag;
}

// ---------------------------------------------------------------------------
// enc v4: fused encoder + segment-sum, barrier-free, ONE 64-row tile per
// block, grid = 1600 (6.25 blocks/CU -> 16 waves/CU at VGPR~124; R3's
// EGRID=400 starved the machine at 1 wave/SIMD).
// Wave w: B-fragments for its 64 cols live in 64 VGPRs (one Bsw read);
// A-fragments read straight from global (quads of a row cover one 128B line).
// No LDS, no __syncthreads.
// ---------------------------------------------------------------------------
__global__ __launch_bounds__(256) void enc_kernel(const float* __restrict__ x,
                                                  const int* __restrict__ batch,
                                                  const __bf16* __restrict__ Bsw,
                                                  const float* __restrict__ b_enc,
                                                  float* __restrict__ seg) {
  const int t    = threadIdx.x;
  const int lane = t & 63, wave = t >> 6;
  const int m = lane & 15, quad = lane >> 4;

  const size_t base = (size_t)blockIdx.x * 64;
  const int g0 = batch[base], g63 = batch[base + 63];

  // resident B fragments: [kk][ntl], 64 VGPRs
  bf16x8 bfr[4][4];
#pragma unroll
  for (int kk = 0; kk < 4; ++kk)
#pragma unroll
    for (int ntl = 0; ntl < 4; ++ntl)
      bfr[kk][ntl] =
          *(const bf16x8*)(Bsw + (size_t)(((kk * 16 + wave * 4 + ntl) * 64) + lane) * 8);

  float bias[4];
#pragma unroll
  for (int ntl = 0; ntl < 4; ++ntl) bias[ntl] = b_enc[(wave * 4 + ntl) * 16 + m];

  f32x4 acc[4][4];   // [ntl][mt]
#pragma unroll
  for (int a = 0; a < 4; ++a)
#pragma unroll
    for (int b = 0; b < 4; ++b) acc[a][b] = (f32x4){0.f, 0.f, 0.f, 0.f};

#pragma unroll
  for (int kk = 0; kk < 4; ++kk) {
    bf16x8 afr[4];
#pragma unroll
    for (int mt = 0; mt < 4; ++mt) {
      const float* src = x + (base + mt * 16 + m) * DDIM + kk * 32 + quad * 8;
      float4 lo = *(const float4*)src;
      float4 hi = *(const float4*)(src + 4);
      bf16x8 a;
      a[0] = (__bf16)lo.x; a[1] = (__bf16)lo.y; a[2] = (__bf16)lo.z; a[3] = (__bf16)lo.w;
      a[4] = (__bf16)hi.x; a[5] = (__bf16)hi.y; a[6] = (__bf16)hi.z; a[7] = (__bf16)hi.w;
      afr[mt] = a;
    }
#pragma unroll
    for (int ntl = 0; ntl < 4; ++ntl)
#pragma unroll
      for (int mt = 0; mt < 4; ++mt)
        acc[ntl][mt] = __builtin_amdgcn_mfma_f32_16x16x32_bf16(
            afr[mt], bfr[kk][ntl], acc[ntl][mt], 0, 0, 0);
  }

  // epilogue: relu + bias, segment-reduce the 64 rows (block-uniform branch)
  if (g0 == g63) {
#pragma unroll
    for (int ntl = 0; ntl < 4; ++ntl) {
      float s = 0.f;
#pragma unroll
      for (int mt = 0; mt < 4; ++mt)
#pragma unroll
        for (int r = 0; r < 4; ++r)
          s += fmaxf(acc[ntl][mt][r] + bias[ntl], 0.f);
      s += __shfl_xor(s, 16, 64);
      s += __shfl_xor(s, 32, 64);
      if (quad == 0) atomicAdd(&seg[g0 * HDIM + (wave * 4 + ntl) * 16 + m], s);
    }
  } else {
    int gl[16];
#pragma unroll
    for (int mt = 0; mt < 4; ++mt)
#pragma unroll
      for (int r = 0; r < 4; ++r) gl[mt * 4 + r] = batch[base + mt * 16 + quad * 4 + r];
#pragma unroll
    for (int ntl = 0; ntl < 4; ++ntl) {
      const int col = (wave * 4 + ntl) * 16 + m;
      int   grun = gl[0];
      float s    = 0.f;
#pragma unroll
      for (int mt = 0; mt < 4; ++mt)
#pragma unroll
        for (int r = 0; r < 4; ++r) {
          int   g = gl[mt * 4 + r];
          float v = fmaxf(acc[ntl][mt][r] + bias[ntl], 0.f);
          if (g != grun) {
            atomicAdd(&seg[grun * HDIM + col], s);
            grun = g; s = v;
          } else {
            s += v;
          }
        }
      atomicAdd(&seg[grun * HDIM + col], s);
    }
  }
}

// ---------------------------------------------------------------------------
// Tail MLP v4 — broadcast-hotspot fix. All 256 blocks read the SAME 896 KB of
// weights; in v2/v3 they did so in identical order simultaneously -> TCC bank
// serialization (33 us vs 6.8 us L2 floor, insensitive to wave count).
// Decorrelate: wave w of block g handles k-chunk (w+g)&7, and starts its
// 32-iter inner loop at offset (g*7)&31 (wrapped). Partials are indexed by
// CHUNK -> reduction order (and fp32 result) identical to v3.
// Biases pre-loaded to registers (no mid-layer global stalls).
// ---------------------------------------------------------------------------
__device__ __forceinline__ void mlp_layer256(const float* __restrict__ buf_in,
                                             float* __restrict__ buf_out,
                                             float* __restrict__ part,  // [8][256]
                                             const float* __restrict__ W,
                                             float bias_t, bool relu,
                                             int t, int crot, int krot) {
  const int w  = t >> 6;
  const int jq = t & 63;
  const int c  = (w + crot) & 7;           // decorrelated k-chunk
  f32x4 acc = {0.f, 0.f, 0.f, 0.f};
  const float4* wbase = (const float4*)(W + (size_t)c * 32 * HDIM) + jq;
#pragma unroll 8
  for (int i = 0; i < 32; ++i) {
    int    k  = (i + krot) & 31;           // decorrelated start within chunk
    float  a  = buf_in[c * 32 + k];        // wave-uniform LDS broadcast
    float4 ww = wbase[(size_t)k * (HDIM / 4)];
    acc[0] += a * ww.x; acc[1] += a * ww.y;
    acc[2] += a * ww.z; acc[3] += a * ww.w;
  }
  *(f32x4*)&part[c * HDIM + jq * 4] = acc;
  __syncthreads();
  if (t < HDIM) {
    float v = 0.f;
#pragma unroll
    for (int r = 0; r < 8; ++r) v += part[r * HDIM + t];
    v += bias_t;
    if (relu) v = fmaxf(v, 0.f);
    buf_out[t] = v;
  }
  __syncthreads();
}

__global__ __launch_bounds__(512) void mlp_kernel(
    const float* __restrict__ seg,
    const float* __restrict__ Wv1, const float* __restrict__ bv1,
    const float* __restrict__ Wv2, const float* __restrict__ bv2,
    const float* __restrict__ Wp1, const float* __restrict__ bp1,
    const float* __restrict__ Wp2, const float* __restrict__ bp2,
    float* __restrict__ out) {
  __shared__ __align__(16) float bufA[HDIM];
  __shared__ __align__(16) float bufB[HDIM];
  __shared__ __align__(16) float part[8 * HDIM];  // viewed as [16][128] in L4
  const int t = threadIdx.x;
  const int g = blockIdx.x;
  const int crot = g & 7;
  const int krot = (g * 7) & 31;

  float myb1 = 0.f, myb2 = 0.f, myb3 = 0.f, myb4 = 0.f;
  if (t < HDIM) {
    myb1 = bv1[t]; myb2 = bv2[t]; myb3 = bp1[t];
    bufA[t] = seg[g * HDIM + t] * 0.125f;
  }
  if (t < ODIM) myb4 = bp2[t];
  __syncthreads();

  mlp_layer256(bufA, bufB, part, Wv1, myb1, true,  t, crot, krot);
  mlp_layer256(bufB, bufA, part, Wv2, myb2, false, t, crot, krot);
  mlp_layer256(bufA, bufB, part, Wp1, myb3, true,  t, crot, krot);

  // layer 4: out[g] = bufB @ Wp2 + bp2, O=128. 16 k-chunks x 32 col-quads.
  {
    const int w  = t >> 5;                 // [0,16)
    const int jq = t & 31;                 // [0,32)
    const int c  = (w + g) & 15;           // decorrelated chunk
    f32x4 acc = {0.f, 0.f, 0.f, 0.f};
    const float4* wbase = (const float4*)(Wp2 + (size_t)c * 16 * ODIM) + jq;
#pragma unroll 8
    for (int k = 0; k < 16; ++k) {
      float  a  = bufB[c * 16 + k];
      float4 ww = wbase[(size_t)k * (ODIM / 4)];
      acc[0] += a * ww.x; acc[1] += a * ww.y;
      acc[2] += a * ww.z; acc[3] += a * ww.w;
    }
    *(f32x4*)&part[c * ODIM + jq * 4] = acc;
    __syncthreads();
    if (t < ODIM) {
      float v = myb4;
#pragma unroll
      for (int r = 0; r < 16; ++r) v += part[r * ODIM + t];
      out[g * ODIM + t] = v;
    }
  }
}

// ---------------------------------------------------------------------------
extern "C" void kernel_launch(void* const* d_in, const int* in_sizes, int n_in,
                              void* d_out, int out_size, void* d_ws, size_t ws_size,
                              hipStream_t stream) {
  const float* x     = (const float*)d_in[0];
  // d_in[1] = edge_index : unused by the reference
  const int*   batch = (const int*)d_in[2];
  const float* W_enc = (const float*)d_in[3];
  const float* b_enc = (const float*)d_in[4];
  const float* W_v1  = (const float*)d_in[5];
  const float* b_v1  = (const float*)d_in[6];
  const float* W_v2  = (const float*)d_in[7];
  const float* b_v2  = (const float*)d_in[8];
  const float* W_p1  = (const float*)d_in[9];
  const float* b_p1  = (const float*)d_in[10];
  const float* W_p2  = (const float*)d_in[11];
  const float* b_p2  = (const float*)d_in[12];
  float* out = (float*)d_out;

  float*  seg = (float*)d_ws;                        // 256*256*4 = 262144 B
  __bf16* Bsw = (__bf16*)((char*)d_ws + 262144);     // 128*256*2 =  65536 B

  prep_kernel<<<16, 256, 0, stream>>>(W_enc, Bsw, seg);
  enc_kernel<<<NTILES, 256, 0, stream>>>(x, batch, Bsw, b_enc, seg);
  mlp_kernel<<<NGRAPH, 512, 0, stream>>>(seg, W_v1, b_v1, W_v2, b_v2,
                                         W_p1, b_p1, W_p2, b_p2, out);
}

// Round 5
// 143.463 us; speedup vs baseline: 1.0578x; 1.0578x over previous
//
#include <hip/hip_runtime.h>

typedef __bf16 bf16x8 __attribute__((ext_vector_type(8)));
typedef __bf16 bf16x4 __attribute__((ext_vector_type(4)));
typedef float  f32x4  __attribute__((ext_vector_type(4)));

#define NGRAPH 256
#define HDIM   256
#define DDIM   128
#define ODIM   128
#define NNODE  102400
#define NTILES 1600          // NNODE / 64

// workspace layout (bytes)
#define WS_SEGX  0           // 256 KB: atomic fallback (zeroed by prep; ~never hit)
#define WS_BSW   262144      // 64 KB : swizzled bf16 W_enc
#define WS_SEG   327680      // 256 KB: final per-graph sums (written by reduce)
#define WS_PARTA 589824      // 1.6 MB: per-tile partial, graph of row 0
#define WS_PARTB 2228224     // 1.6 MB: per-tile partial, graph of row 63

// ---------------------------------------------------------------------------
// prep: zero segX (atomic-fallback buffer) + swizzle W_enc into MFMA
// B-fragment order (bf16).
// Bsw[((kk*16+nt)*64+lane)*8 + j] = W_enc[kk*32+quad*8+j][nt*16+m]
// ---------------------------------------------------------------------------
__global__ __launch_bounds__(256) void prep_kernel(const float* __restrict__ W_enc,
                                                   __bf16* __restrict__ Bsw,
                                                   float* __restrict__ segX) {
  int tid  = blockIdx.x * 256 + threadIdx.x;   // [0, 4096)
  float4 z = {0.f, 0.f, 0.f, 0.f};
#pragma unroll
  for (int p = 0; p < 4; ++p) ((float4*)segX)[tid + p * 4096] = z;

  int lane = tid & 63;
  int t2   = tid >> 6;
  int nt   = t2 & 15;
  int kk   = t2 >> 4;
  int quad = lane >> 4, m = lane & 15;
  int col  = nt * 16 + m;
  bf16x8 frag;
#pragma unroll
  for (int j = 0; j < 8; ++j) {
    int k   = kk * 32 + quad * 8 + j;
    frag[j] = (__bf16)W_enc[k * HDIM + col];
  }
  *(bf16x8*)(Bsw + (size_t)tid * 8) = frag;
}

// ---------------------------------------------------------------------------
// enc_gemm: ATOMIC-FREE encoder tile kernel.
// v2-proven LDS staging for the A-tile (bf16, padded stride 136) + v4's
// register-resident B fragments. Epilogue: relu+bias, reduce the 64 rows into
// at most two per-tile partial vectors (graph of row 0 -> partA, graph of
// row 63 -> partB; partB=0 for single-graph tiles) with PLAIN stores. Rows of
// a third "middle" graph (statistically impossible: ~400 rows/graph vs 64-row
// tiles) fall back to atomicAdd into segX.
// Theory under test: R1-R4's ~40-50us enc invariance = serialized RMW churn
// on seg's 4096 cache lines backing up the TCC/VMEM path.
// ---------------------------------------------------------------------------
__global__ __launch_bounds__(256) void enc_gemm(const float* __restrict__ x,
                                                const int* __restrict__ batch,
                                                const __bf16* __restrict__ Bsw,
                                                const float* __restrict__ b_enc,
                                                float* __restrict__ partA,
                                                float* __restrict__ partB,
                                                float* __restrict__ segX) {
  __shared__ __align__(16) __bf16 Albuf[64 * 136];
  __shared__ int gbuf[64];
  const int    t    = threadIdx.x;
  const int    tile = blockIdx.x;
  const size_t base = (size_t)tile * 64;

  const int lane = t & 63, wave = t >> 6;
  const int m = lane & 15, quad = lane >> 4;

  // resident B fragments for this wave's 64 cols: [kk][ntl] (64 VGPRs)
  bf16x8 bfr[4][4];
#pragma unroll
  for (int kk = 0; kk < 4; ++kk)
#pragma unroll
    for (int ntl = 0; ntl < 4; ++ntl)
      bfr[kk][ntl] =
          *(const bf16x8*)(Bsw + (size_t)(((kk * 16 + wave * 4 + ntl) * 64) + lane) * 8);

  float bias[4];
#pragma unroll
  for (int ntl = 0; ntl < 4; ++ntl) bias[ntl] = b_enc[(wave * 4 + ntl) * 16 + m];

  // stage 64x128 fp32 -> bf16 into LDS (coalesced: lane i loads float4 i)
  const float4* xsrc = (const float4*)(x + base * DDIM);
#pragma unroll
  for (int p = 0; p < 8; ++p) {
    int    i   = t + p * 256;          // float4 index; 32 per row
    float4 v   = xsrc[i];
    int    row = i >> 5, c4 = i & 31;
    bf16x4 bv;
    bv[0] = (__bf16)v.x; bv[1] = (__bf16)v.y;
    bv[2] = (__bf16)v.z; bv[3] = (__bf16)v.w;
    *(bf16x4*)&Albuf[row * 136 + c4 * 4] = bv;
  }
  if (t < 64) gbuf[t] = batch[base + t];
  __syncthreads();

  f32x4 acc[4][4];   // [ntl][mt]
#pragma unroll
  for (int a = 0; a < 4; ++a)
#pragma unroll
    for (int b = 0; b < 4; ++b) acc[a][b] = (f32x4){0.f, 0.f, 0.f, 0.f};

#pragma unroll
  for (int kk = 0; kk < 4; ++kk) {
    bf16x8 afr[4];
#pragma unroll
    for (int mt = 0; mt < 4; ++mt)
      afr[mt] = *(const bf16x8*)&Albuf[(mt * 16 + m) * 136 + kk * 32 + quad * 8];
#pragma unroll
    for (int ntl = 0; ntl < 4; ++ntl)
#pragma unroll
      for (int mt = 0; mt < 4; ++mt)
        acc[ntl][mt] = __builtin_amdgcn_mfma_f32_16x16x32_bf16(
            afr[mt], bfr[kk][ntl], acc[ntl][mt], 0, 0, 0);
  }

  // ---- epilogue: relu+bias, split rows by graph, plain-store partials ----
  const int  g0  = gbuf[0], g63 = gbuf[63];
  const bool uni = (g0 == g63);

  int gl[16];
  if (!uni) {
#pragma unroll
    for (int mt = 0; mt < 4; ++mt)
#pragma unroll
      for (int r = 0; r < 4; ++r) gl[mt * 4 + r] = gbuf[mt * 16 + quad * 4 + r];
  }

#pragma unroll
  for (int ntl = 0; ntl < 4; ++ntl) {
    const int col = (wave * 4 + ntl) * 16 + m;
    float sA = 0.f, sB = 0.f;
    if (uni) {
#pragma unroll
      for (int mt = 0; mt < 4; ++mt)
#pragma unroll
        for (int r = 0; r < 4; ++r)
          sA += fmaxf(acc[ntl][mt][r] + bias[ntl], 0.f);
    } else {
#pragma unroll
      for (int mt = 0; mt < 4; ++mt)
#pragma unroll
        for (int r = 0; r < 4; ++r) {
          int   g = gl[mt * 4 + r];
          float v = fmaxf(acc[ntl][mt][r] + bias[ntl], 0.f);
          if (g == g0)       sA += v;
          else if (g == g63) sB += v;
          else atomicAdd(&segX[g * HDIM + col], v);   // ~never taken
        }
    }
    sA += __shfl_xor(sA, 16, 64);
    sA += __shfl_xor(sA, 32, 64);
    sB += __shfl_xor(sB, 16, 64);
    sB += __shfl_xor(sB, 32, 64);
    if (quad == 0) {
      partA[(size_t)tile * HDIM + col] = sA;
      partB[(size_t)tile * HDIM + col] = sB;
    }
  }
}

// ---------------------------------------------------------------------------
// reduce: one block per graph. Binary-search batch for the graph's row range,
// then sum the overlapping tiles' partials. seg[g][c] = segX[g][c] +
// sum_t(partA[t][c] if g0(t)==g) + sum_t(partB[t][c] if g63(t)==g).
// ~7 tiles per graph -> trivial.
// ---------------------------------------------------------------------------
__global__ __launch_bounds__(256) void reduce_kernel(const int* __restrict__ batch,
                                                     const float* __restrict__ partA,
                                                     const float* __restrict__ partB,
                                                     const float* __restrict__ segX,
                                                     float* __restrict__ seg) {
  const int g = blockIdx.x, c = threadIdx.x;

  int lo = 0, hi = NNODE;                 // lower_bound(batch, g)
  while (lo < hi) { int mid = (lo + hi) >> 1; if (batch[mid] < g) lo = mid + 1; else hi = mid; }
  const int start = lo;
  hi = NNODE;                             // lower_bound(batch, g+1)
  while (lo < hi) { int mid = (lo + hi) >> 1; if (batch[mid] < g + 1) lo = mid + 1; else hi = mid; }
  const int end = lo;

  float s = segX[g * HDIM + c];
  if (end > start) {
    const int t0 = start >> 6, t1 = (end - 1) >> 6;
    for (int t = t0; t <= t1; ++t) {
      if (batch[t * 64] == g)      s += partA[(size_t)t * HDIM + c];
      if (batch[t * 64 + 63] == g) s += partB[(size_t)t * HDIM + c];
    }
  }
  seg[g * HDIM + c] = s;
}

// ---------------------------------------------------------------------------
// Tail MLP v5: v3 structure (sequential chunks — R4's decorrelation regressed)
// with register-resident biases. 512 threads = 8 waves.
// ---------------------------------------------------------------------------
__device__ __forceinline__ void mlp_layer256(const float* __restrict__ buf_in,
                                             float* __restrict__ buf_out,
                                             float* __restrict__ part,  // [8][256]
                                             const float* __restrict__ W,
                                             float bias_t, bool relu, int t) {
  const int w  = t >> 6;
  const int jq = t & 63;
  f32x4 acc = {0.f, 0.f, 0.f, 0.f};
  const float4* wrow = (const float4*)(W + (size_t)w * 32 * HDIM) + jq;
#pragma unroll 8
  for (int k = 0; k < 32; ++k) {
    float  a  = buf_in[w * 32 + k];          // wave-uniform LDS broadcast
    float4 ww = wrow[(size_t)k * (HDIM / 4)];
    acc[0] += a * ww.x; acc[1] += a * ww.y;
    acc[2] += a * ww.z; acc[3] += a * ww.w;
  }
  *(f32x4*)&part[w * HDIM + jq * 4] = acc;
  __syncthreads();
  if (t < HDIM) {
    float v = 0.f;
#pragma unroll
    for (int r = 0; r < 8; ++r) v += part[r * HDIM + t];
    v += bias_t;
    if (relu) v = fmaxf(v, 0.f);
    buf_out[t] = v;
  }
  __syncthreads();
}

__global__ __launch_bounds__(512) void mlp_kernel(
    const float* __restrict__ seg,
    const float* __restrict__ Wv1, const float* __restrict__ bv1,
    const float* __restrict__ Wv2, const float* __restrict__ bv2,
    const float* __restrict__ Wp1, const float* __restrict__ bp1,
    const float* __restrict__ Wp2, const float* __restrict__ bp2,
    float* __restrict__ out) {
  __shared__ __align__(16) float bufA[HDIM];
  __shared__ __align__(16) float bufB[HDIM];
  __shared__ __align__(16) float part[8 * HDIM];  // viewed as [16][128] in L4
  const int t = threadIdx.x;
  const int g = blockIdx.x;

  float myb1 = 0.f, myb2 = 0.f, myb3 = 0.f, myb4 = 0.f;
  if (t < HDIM) {
    myb1 = bv1[t]; myb2 = bv2[t]; myb3 = bp1[t];
    bufA[t] = seg[g * HDIM + t] * 0.125f;
  }
  if (t < ODIM) myb4 = bp2[t];
  __syncthreads();

  mlp_layer256(bufA, bufB, part, Wv1, myb1, true,  t);
  mlp_layer256(bufB, bufA, part, Wv2, myb2, false, t);
  mlp_layer256(bufA, bufB, part, Wp1, myb3, true,  t);

  // layer 4: out[g] = bufB @ Wp2 + bp2, O=128. 16 k-chunks x 32 col-quads.
  {
    const int w  = t >> 5;
    const int jq = t & 31;
    f32x4 acc = {0.f, 0.f, 0.f, 0.f};
    const float4* wrow = (const float4*)(Wp2 + (size_t)w * 16 * ODIM) + jq;
#pragma unroll 8
    for (int k = 0; k < 16; ++k) {
      float  a  = bufB[w * 16 + k];
      float4 ww = wrow[(size_t)k * (ODIM / 4)];
      acc[0] += a * ww.x; acc[1] += a * ww.y;
      acc[2] += a * ww.z; acc[3] += a * ww.w;
    }
    *(f32x4*)&part[w * ODIM + jq * 4] = acc;
    __syncthreads();
    if (t < ODIM) {
      float v = myb4;
#pragma unroll
      for (int r = 0; r < 16; ++r) v += part[r * ODIM + t];
      out[g * ODIM + t] = v;
    }
  }
}

// ---------------------------------------------------------------------------
extern "C" void kernel_launch(void* const* d_in, const int* in_sizes, int n_in,
                              void* d_out, int out_size, void* d_ws, size_t ws_size,
                              hipStream_t stream) {
  const float* x     = (const float*)d_in[0];
  // d_in[1] = edge_index : unused by the reference
  const int*   batch = (const int*)d_in[2];
  const float* W_enc = (const float*)d_in[3];
  const float* b_enc = (const float*)d_in[4];
  const float* W_v1  = (const float*)d_in[5];
  const float* b_v1  = (const float*)d_in[6];
  const float* W_v2  = (const float*)d_in[7];
  const float* b_v2  = (const float*)d_in[8];
  const float* W_p1  = (const float*)d_in[9];
  const float* b_p1  = (const float*)d_in[10];
  const float* W_p2  = (const float*)d_in[11];
  const float* b_p2  = (const float*)d_in[12];
  float* out = (float*)d_out;

  float*  segX  = (float*)((char*)d_ws + WS_SEGX);
  __bf16* Bsw   = (__bf16*)((char*)d_ws + WS_BSW);
  float*  seg   = (float*)((char*)d_ws + WS_SEG);
  float*  partA = (float*)((char*)d_ws + WS_PARTA);
  float*  partB = (float*)((char*)d_ws + WS_PARTB);

  prep_kernel<<<16, 256, 0, stream>>>(W_enc, Bsw, segX);
  enc_gemm<<<NTILES, 256, 0, stream>>>(x, batch, Bsw, b_enc, partA, partB, segX);
  reduce_kernel<<<NGRAPH, 256, 0, stream>>>(batch, partA, partB, segX, seg);
  mlp_kernel<<<NGRAPH, 512, 0, stream>>>(seg, W_v1, b_v1, W_v2, b_v2,
                                         W_p1, b_p1, W_p2, b_p2, out);
}